// Round 15
// baseline (46.590 us; speedup 1.0000x reference)
//
#include <hip/hip_runtime.h>
#include <hip/hip_bf16.h>

#define J_DIM 25
#define T_DIM 120
#define O_DIM 64
#define KPAD  328        // bf16 per ys/Wf row; 656 B rows
#define TB    48         // t-rows per block; chunks at t0 = 0,36,72 (overlaps dup-stored)
#define WROWS 52         // staged window rows (row + w <= 51)
#define XPAD  20         // xs row pad (floats)

typedef __attribute__((ext_vector_type(8))) short bf16x8;
typedef __attribute__((ext_vector_type(4))) float f32x4;

__device__ __forceinline__ unsigned f2bf(float f) {
    union { float f; unsigned u; } v; v.f = f;
    return (v.u + 0x7FFFu + ((v.u >> 16) & 1u)) >> 16;
}
__device__ __forceinline__ unsigned pk2(float lo, float hi) {
    __hip_bfloat162 h = __float22bfloat162_rn(float2{lo, hi});
    unsigned u;
    __builtin_memcpy(&u, &h, 4);
    return u;
}

// ---- W (306x64 f32) -> Wf[o][k], k = 18a + b; b<17: 0.5*W2[a,b]; b==17: W1[a] ----
__global__ void wprep(const float* __restrict__ W, unsigned short* __restrict__ Wf) {
    int i = blockIdx.x * 256 + threadIdx.x;
    if (i >= O_DIM * KPAD) return;
    int o = i / KPAD, k = i % KPAD;
    int a = k / 18, b = k % 18;
    float v = 0.0f;
    if (k < 306) v = (b == 17) ? W[a * O_DIM + o] : 0.5f * W[(17 + 17 * a + b) * O_DIM + o];
    Wf[o * KPAD + k] = (unsigned short)f2bf(v);
}

// ---- main: block = (n, j, 48-row chunk); 256 threads; flat 2-barrier structure ----
// Baked-in lessons: launch_bounds must not clamp VGPR below ~90 (R6/R10 spill
// catastrophe); phase bodies stay flat, no cross-phase live state in loops
// (R8/R9/R13); slot-loop phase 1 is allocator-safe (R12/R14).
__global__ __launch_bounds__(256, 4) void sig_mfma(
    const float* __restrict__ x, const unsigned short* __restrict__ Wf,
    const float* __restrict__ bias, float* __restrict__ out)
{
    __shared__ float xs[WROWS][XPAD];            // 4,160 B
    __shared__ unsigned short ys[TB * KPAD];     // 31,488 B   (total 35.6 KB -> 4 blk/CU)

    const int tid = threadIdx.x;
    const int bid = blockIdx.x;
    const int chunk = bid % 3;
    const int j = (bid / 3) % J_DIM;
    const int n = bid / (3 * J_DIM);
    const int t0 = chunk * 36;                   // 0, 36, 72
    const int wave = tid >> 6, lane = tid & 63;
    const int l15 = lane & 15, l4 = lane >> 4;

    // ---- stage xs[i][c] = x[n,c,j,clamp(t0-2+i)] ----
    const float* xbase = x + ((size_t)(n * 16) * J_DIM + j) * T_DIM;
    for (int idx = tid; idx < 16 * WROWS; idx += 256) {
        int c = idx / WROWS, i = idx % WROWS;
        int st = min(max(t0 - 2 + i, 0), T_DIM - 1);
        xs[i][c] = xbase[(size_t)c * J_DIM * T_DIM + st];
    }
    // zero pad bytes [608,656) of every row (608-611 re-written by time-row pass)
    if (tid < TB * 3) {
        int r = tid / 3, p = tid % 3;
        *(uint4*)((char*)ys + r * 656 + 608 + p * 16) = uint4{0, 0, 0, 0};
    }
    __syncthreads();

    // ---- phase 1a: 384 slots (row 0..47, q 0..7) -> S2 rows a = 2q, 2q+1 ----
    // S2[a,b] = sum_w h_w[a] * p_w[b],  h = (-p1, p0-p2, p1-p3, p2-p4, p3+p4)
    #pragma unroll 1
    for (int s = tid; s < TB * 8; s += 256) {
        const int row = s >> 3, q = s & 7;
        const int t = t0 + row;
        const int start = max(t - 2, 0), end = min(t + 3, T_DIM);
        const float inv = 1.0f / (float)(end - start - 1);
        float ptv[5];
        #pragma unroll
        for (int w = 0; w < 5; ++w) {
            int pcw = min(max(t - 2 + w, 0), T_DIM - 1);
            ptv[w] = (float)(pcw - start) * inv;
        }
        float pa0[5], pa1[5];
        #pragma unroll
        for (int w = 0; w < 5; ++w) {
            float2 pr = *(const float2*)&xs[row + w][2 * q];
            pa0[w] = pr.x; pa1[w] = pr.y;
        }
        float h0[5], h1[5];
        h0[0] = -pa0[1];          h1[0] = -pa1[1];
        h0[1] = pa0[0] - pa0[2];  h1[1] = pa1[0] - pa1[2];
        h0[2] = pa0[1] - pa0[3];  h1[2] = pa1[1] - pa1[3];
        h0[3] = pa0[2] - pa0[4];  h1[3] = pa1[2] - pa1[4];
        h0[4] = pa0[3] + pa0[4];  h1[4] = pa1[3] + pa1[4];

        unsigned u0[9], u1[9];
        float accp0 = 0, accp1 = 0;
        #pragma unroll
        for (int hb = 0; hb < 2; ++hb) {
            float4 xw[5][2];
            #pragma unroll
            for (int w = 0; w < 5; ++w) {
                const float* rw = &xs[row + w][0];
                xw[w][0] = *(const float4*)(rw + 8 * hb);
                xw[w][1] = *(const float4*)(rw + 8 * hb + 4);
            }
            #pragma unroll
            for (int b8 = 0; b8 < 8; ++b8) {
                float pb[5];
                #pragma unroll
                for (int w = 0; w < 5; ++w) {
                    float4 v = xw[w][b8 >> 2];
                    pb[w] = ((b8 & 3) == 0) ? v.x : ((b8 & 3) == 1) ? v.y
                          : ((b8 & 3) == 2) ? v.z : v.w;
                }
                float a0 = h0[0] * pb[0], a1 = h1[0] * pb[0];
                #pragma unroll
                for (int w = 1; w < 5; ++w) {
                    a0 = fmaf(h0[w], pb[w], a0);
                    a1 = fmaf(h1[w], pb[w], a1);
                }
                const int b = hb * 8 + b8;
                if (b & 1) {
                    const int m = b >> 1;
                    u0[m] = pk2(accp0, a0);
                    u1[m] = pk2(accp1, a1);
                } else { accp0 = a0; accp1 = a1; }
            }
        }
        {   // b = 16 (time column) + S1 slot
            float a0 = h0[0] * ptv[0], a1 = h1[0] * ptv[0];
            #pragma unroll
            for (int w = 1; w < 5; ++w) {
                a0 = fmaf(h0[w], ptv[w], a0);
                a1 = fmaf(h1[w], ptv[w], a1);
            }
            u0[8] = pk2(a0, pa0[4]);
            u1[8] = pk2(a1, pa1[4]);
        }
        char* yr = (char*)ys + row * 656 + 72 * q;   // rows 2q,2q+1: contiguous 72 B
        *(uint2*)(yr +  0) = uint2{u0[0], u0[1]};
        *(uint2*)(yr +  8) = uint2{u0[2], u0[3]};
        *(uint2*)(yr + 16) = uint2{u0[4], u0[5]};
        *(uint2*)(yr + 24) = uint2{u0[6], u0[7]};
        *(uint2*)(yr + 32) = uint2{u0[8], u1[0]};
        *(uint2*)(yr + 40) = uint2{u1[1], u1[2]};
        *(uint2*)(yr + 48) = uint2{u1[3], u1[4]};
        *(uint2*)(yr + 56) = uint2{u1[5], u1[6]};
        *(uint2*)(yr + 64) = uint2{u1[7], u1[8]};
    }

    // ---- phase 1b: time-row a=16, computed ONCE per t (threads 0..47) ----
    if (tid < TB) {
        const int row = tid;
        const int t = t0 + row;
        const int start = max(t - 2, 0), end = min(t + 3, T_DIM);
        const float inv = 1.0f / (float)(end - start - 1);
        float ptv[5];
        #pragma unroll
        for (int w = 0; w < 5; ++w) {
            int pcw = min(max(t - 2 + w, 0), T_DIM - 1);
            ptv[w] = (float)(pcw - start) * inv;
        }
        float ht[5];
        ht[0] = -ptv[1];
        ht[1] = ptv[0] - ptv[2];
        ht[2] = ptv[1] - ptv[3];
        ht[3] = ptv[2] - ptv[4];
        ht[4] = ptv[3] + ptv[4];

        unsigned ut[9];
        float accpt = 0;
        #pragma unroll
        for (int hb = 0; hb < 2; ++hb) {
            float4 xw[5][2];
            #pragma unroll
            for (int w = 0; w < 5; ++w) {
                const float* rw = &xs[row + w][0];
                xw[w][0] = *(const float4*)(rw + 8 * hb);
                xw[w][1] = *(const float4*)(rw + 8 * hb + 4);
            }
            #pragma unroll
            for (int b8 = 0; b8 < 8; ++b8) {
                float pb[5];
                #pragma unroll
                for (int w = 0; w < 5; ++w) {
                    float4 v = xw[w][b8 >> 2];
                    pb[w] = ((b8 & 3) == 0) ? v.x : ((b8 & 3) == 1) ? v.y
                          : ((b8 & 3) == 2) ? v.z : v.w;
                }
                float at = ht[0] * pb[0];
                #pragma unroll
                for (int w = 1; w < 5; ++w) at = fmaf(ht[w], pb[w], at);
                const int b = hb * 8 + b8;
                if (b & 1) ut[b >> 1] = pk2(accpt, at);
                else       accpt = at;
            }
        }
        {   // b = 16 + S1 slot (time path last point)
            float at = ht[0] * ptv[0];
            #pragma unroll
            for (int w = 1; w < 5; ++w) at = fmaf(ht[w], ptv[w], at);
            ut[8] = pk2(at, ptv[4]);
        }
        char* yr16 = (char*)ys + row * 656 + 576;    // row a=16: bytes [576,612)
        *(uint2*)(yr16 +  0) = uint2{ut[0], ut[1]};
        *(uint2*)(yr16 +  8) = uint2{ut[2], ut[3]};
        *(uint2*)(yr16 + 16) = uint2{ut[4], ut[5]};
        *(uint2*)(yr16 + 24) = uint2{ut[6], ut[7]};
        *(unsigned*)(yr16 + 32) = ut[8];
    }
    __syncthreads();

    // ---- phase 2: wave = o-quarter; B-frags loaded once, reused over 3 M-tiles ----
    {
        const float bv = bias[wave * 16 + l15];
        const unsigned short* Bb = Wf + (size_t)(wave * 16 + l15) * KPAD + l4 * 8;
        bf16x8 bfrag[10];
        #pragma unroll
        for (int kk = 0; kk < 10; ++kk)
            bfrag[kk] = *(const bf16x8*)(Bb + kk * 32);
        #pragma unroll
        for (int mi = 0; mi < 3; ++mi) {
            const char* Ab = (const char*)ys + (mi * 16 + l15) * 656 + l4 * 16;
            f32x4 acc = f32x4{bv, bv, bv, bv};
            #pragma unroll
            for (int kk = 0; kk < 10; ++kk) {
                bf16x8 af = *(const bf16x8*)(Ab + kk * 64);
                acc = __builtin_amdgcn_mfma_f32_16x16x32_bf16(af, bfrag[kk], acc, 0, 0, 0);
            }
            const int tg = t0 + mi * 16 + l4 * 4;    // row = l4*4 + reg -> t
            float* op = out + ((size_t)(n * O_DIM + wave * 16 + l15) * J_DIM + j) * T_DIM + tg;
            *(f32x4*)op = acc;
        }
    }
}

extern "C" void kernel_launch(void* const* d_in, const int* in_sizes, int n_in,
                              void* d_out, int out_size, void* d_ws, size_t ws_size,
                              hipStream_t stream) {
    const float* x = (const float*)d_in[0];
    const float* W = (const float*)d_in[1];
    const float* b = (const float*)d_in[2];
    float* out = (float*)d_out;
    unsigned short* Wf = (unsigned short*)d_ws;   // 64*328*2 = 41,984 B

    wprep<<<(O_DIM * KPAD + 255) / 256, 256, 0, stream>>>(W, Wf);
    sig_mfma<<<64 * J_DIM * 3, 256, 0, stream>>>(x, Wf, b, out);
}

// Round 16
// 45.846 us; speedup vs baseline: 1.0162x; 1.0162x over previous
//
#include <hip/hip_runtime.h>
#include <hip/hip_bf16.h>

#define J_DIM 25
#define T_DIM 120
#define O_DIM 64
#define KPAD  328        // bf16 per ys/Wf row; 656 B = 41*16 (b128-aligned, 2-way banks)
#define TB    40         // t-rows per block; 3 exact chunks, zero dup phase-1 work
#define WROWS 44         // staged window rows (row + w <= 43)
#define XPAD  20         // xs row pad (floats)

typedef __attribute__((ext_vector_type(8))) short bf16x8;
typedef __attribute__((ext_vector_type(4))) float f32x4;

__device__ __forceinline__ unsigned f2bf(float f) {
    union { float f; unsigned u; } v; v.f = f;
    return (v.u + 0x7FFFu + ((v.u >> 16) & 1u)) >> 16;
}
__device__ __forceinline__ unsigned pk2(float lo, float hi) {
    __hip_bfloat162 h = __float22bfloat162_rn(float2{lo, hi});
    unsigned u;
    __builtin_memcpy(&u, &h, 4);
    return u;
}

// ---- W (306x64 f32) -> Wf[o][k], k = 18a + b; b<17: 0.5*W2[a,b]; b==17: W1[a] ----
__global__ void wprep(const float* __restrict__ W, unsigned short* __restrict__ Wf) {
    int i = blockIdx.x * 256 + threadIdx.x;
    if (i >= O_DIM * KPAD) return;
    int o = i / KPAD, k = i % KPAD;
    int a = k / 18, b = k % 18;
    float v = 0.0f;
    if (k < 306) v = (b == 17) ? W[a * O_DIM + o] : 0.5f * W[(17 + 17 * a + b) * O_DIM + o];
    Wf[o * KPAD + k] = (unsigned short)f2bf(v);
}

// ---- main: block = (n, j, 40-row chunk); 256 threads; flat 2-barrier structure ----
// Baked-in lessons: launch_bounds must not clamp VGPR below need (R6/R10 spill
// catastrophe); phase bodies stay flat, no cross-phase live state in loops
// (R8/R9/R13); slot-loop phase 1 is allocator-safe (R12/R14).
__global__ __launch_bounds__(256, 4) void sig_mfma(
    const float* __restrict__ x, const unsigned short* __restrict__ Wf,
    const float* __restrict__ bias, float* __restrict__ out)
{
    __shared__ float xs[WROWS][XPAD];            // 3,520 B
    __shared__ unsigned short ys[TB * KPAD];     // 26,240 B   (total 29.8 KB -> 5 blk/CU)

    const int tid = threadIdx.x;
    const int bid = blockIdx.x;
    const int chunk = bid % 3;
    const int j = (bid / 3) % J_DIM;
    const int n = bid / (3 * J_DIM);
    const int t0 = chunk * TB;                   // 0, 40, 80 — exact tiling
    const int wave = tid >> 6, lane = tid & 63;
    const int l15 = lane & 15, l4 = lane >> 4;

    // ---- stage xs[i][c] = x[n,c,j,clamp(t0-2+i)] ----
    const float* xbase = x + ((size_t)(n * 16) * J_DIM + j) * T_DIM;
    for (int idx = tid; idx < 16 * WROWS; idx += 256) {
        int c = idx / WROWS, i = idx % WROWS;
        int st = min(max(t0 - 2 + i, 0), T_DIM - 1);
        xs[i][c] = xbase[(size_t)c * J_DIM * T_DIM + st];
    }
    // zero pad bytes [608,656) of every row (608-611 re-written by row-16 store)
    if (tid < TB * 3) {
        int r = tid / 3, p = tid % 3;
        *(uint4*)((char*)ys + r * 656 + 608 + p * 16) = uint4{0, 0, 0, 0};
    }
    __syncthreads();

    // ---- phase 1: 320 slots (row 0..39, q 0..7); thread does slot tid (+256) ----
    // S2[a,b] = sum_w h_w[a] * p_w[b],  h = (-p1, p0-p2, p1-p3, p2-p4, p3+p4)
    #pragma unroll 1
    for (int s = tid; s < TB * 8; s += 256) {
        const int row = s >> 3, q = s & 7;
        const int t = t0 + row;
        const int start = max(t - 2, 0), end = min(t + 3, T_DIM);
        const float inv = 1.0f / (float)(end - start - 1);
        float ptv[5];
        #pragma unroll
        for (int w = 0; w < 5; ++w) {
            int pcw = min(max(t - 2 + w, 0), T_DIM - 1);
            ptv[w] = (float)(pcw - start) * inv;
        }
        float pa0[5], pa1[5];
        #pragma unroll
        for (int w = 0; w < 5; ++w) {
            float2 pr = *(const float2*)&xs[row + w][2 * q];
            pa0[w] = pr.x; pa1[w] = pr.y;
        }
        float h0[5], h1[5], ht[5];
        h0[0] = -pa0[1];          h1[0] = -pa1[1];          ht[0] = -ptv[1];
        h0[1] = pa0[0] - pa0[2];  h1[1] = pa1[0] - pa1[2];  ht[1] = ptv[0] - ptv[2];
        h0[2] = pa0[1] - pa0[3];  h1[2] = pa1[1] - pa1[3];  ht[2] = ptv[1] - ptv[3];
        h0[3] = pa0[2] - pa0[4];  h1[3] = pa1[2] - pa1[4];  ht[3] = ptv[2] - ptv[4];
        h0[4] = pa0[3] + pa0[4];  h1[4] = pa1[3] + pa1[4];  ht[4] = ptv[3] + ptv[4];

        unsigned u0[9], u1[9], ut[9];
        float accp0 = 0, accp1 = 0, accpt = 0;
        #pragma unroll
        for (int hb = 0; hb < 2; ++hb) {
            float4 xw[5][2];
            #pragma unroll
            for (int w = 0; w < 5; ++w) {
                const float* rw = &xs[row + w][0];
                xw[w][0] = *(const float4*)(rw + 8 * hb);
                xw[w][1] = *(const float4*)(rw + 8 * hb + 4);
            }
            #pragma unroll
            for (int b8 = 0; b8 < 8; ++b8) {
                float pb[5];
                #pragma unroll
                for (int w = 0; w < 5; ++w) {
                    float4 v = xw[w][b8 >> 2];
                    pb[w] = ((b8 & 3) == 0) ? v.x : ((b8 & 3) == 1) ? v.y
                          : ((b8 & 3) == 2) ? v.z : v.w;
                }
                float a0 = h0[0] * pb[0], a1 = h1[0] * pb[0], at = ht[0] * pb[0];
                #pragma unroll
                for (int w = 1; w < 5; ++w) {
                    a0 = fmaf(h0[w], pb[w], a0);
                    a1 = fmaf(h1[w], pb[w], a1);
                    at = fmaf(ht[w], pb[w], at);
                }
                const int b = hb * 8 + b8;
                if (b & 1) {
                    const int m = b >> 1;
                    u0[m] = pk2(accp0, a0);
                    u1[m] = pk2(accp1, a1);
                    ut[m] = pk2(accpt, at);
                } else { accp0 = a0; accp1 = a1; accpt = at; }
            }
        }
        {   // b = 16 (time column) + S1 slot
            float a0 = h0[0] * ptv[0], a1 = h1[0] * ptv[0], at = ht[0] * ptv[0];
            #pragma unroll
            for (int w = 1; w < 5; ++w) {
                a0 = fmaf(h0[w], ptv[w], a0);
                a1 = fmaf(h1[w], ptv[w], a1);
                at = fmaf(ht[w], ptv[w], at);
            }
            u0[8] = pk2(a0, pa0[4]);
            u1[8] = pk2(a1, pa1[4]);
            ut[8] = pk2(at, ptv[4]);
        }
        char* yr = (char*)ys + row * 656 + 72 * q;   // rows 2q,2q+1: contiguous 72 B
        *(uint2*)(yr +  0) = uint2{u0[0], u0[1]};
        *(uint2*)(yr +  8) = uint2{u0[2], u0[3]};
        *(uint2*)(yr + 16) = uint2{u0[4], u0[5]};
        *(uint2*)(yr + 24) = uint2{u0[6], u0[7]};
        *(uint2*)(yr + 32) = uint2{u0[8], u1[0]};
        *(uint2*)(yr + 40) = uint2{u1[1], u1[2]};
        *(uint2*)(yr + 48) = uint2{u1[3], u1[4]};
        *(uint2*)(yr + 56) = uint2{u1[5], u1[6]};
        *(uint2*)(yr + 64) = uint2{u1[7], u1[8]};
        if (q == 0) {                                // row a=16 at bytes [576,612)
            char* yr16 = (char*)ys + row * 656 + 576;
            *(uint2*)(yr16 +  0) = uint2{ut[0], ut[1]};
            *(uint2*)(yr16 +  8) = uint2{ut[2], ut[3]};
            *(uint2*)(yr16 + 16) = uint2{ut[4], ut[5]};
            *(uint2*)(yr16 + 24) = uint2{ut[6], ut[7]};
            *(unsigned*)(yr16 + 32) = ut[8];
        }
    }
    __syncthreads();

    // ---- phase 2: wave = o-quarter; B-frags loaded once; M-tiles at rows {0,16,24} ----
    // third tile re-reads rows 24..39 (in-bounds) and duplicate-stores rows 24..31
    // with identical values (benign) — avoids any out-of-bounds ys access.
    {
        const float bv = bias[wave * 16 + l15];
        const unsigned short* Bb = Wf + (size_t)(wave * 16 + l15) * KPAD + l4 * 8;
        bf16x8 bfrag[10];
        #pragma unroll
        for (int kk = 0; kk < 10; ++kk)
            bfrag[kk] = *(const bf16x8*)(Bb + kk * 32);
        const int moff[3] = {0, 16, 24};
        #pragma unroll
        for (int mi = 0; mi < 3; ++mi) {
            const char* Ab = (const char*)ys + (moff[mi] + l15) * 656 + l4 * 16;
            f32x4 acc = f32x4{bv, bv, bv, bv};
            #pragma unroll
            for (int kk = 0; kk < 10; ++kk) {
                bf16x8 af = *(const bf16x8*)(Ab + kk * 64);
                acc = __builtin_amdgcn_mfma_f32_16x16x32_bf16(af, bfrag[kk], acc, 0, 0, 0);
            }
            const int tg = t0 + moff[mi] + l4 * 4;   // row = l4*4 + reg -> t
            float* op = out + ((size_t)(n * O_DIM + wave * 16 + l15) * J_DIM + j) * T_DIM + tg;
            *(f32x4*)op = acc;
        }
    }
}

extern "C" void kernel_launch(void* const* d_in, const int* in_sizes, int n_in,
                              void* d_out, int out_size, void* d_ws, size_t ws_size,
                              hipStream_t stream) {
    const float* x = (const float*)d_in[0];
    const float* W = (const float*)d_in[1];
    const float* b = (const float*)d_in[2];
    float* out = (float*)d_out;
    unsigned short* Wf = (unsigned short*)d_ws;   // 64*328*2 = 41,984 B

    wprep<<<(O_DIM * KPAD + 255) / 256, 256, 0, stream>>>(W, Wf);
    sig_mfma<<<64 * J_DIM * 3, 256, 0, stream>>>(x, Wf, b, out);
}

// Round 17
// 45.368 us; speedup vs baseline: 1.0269x; 1.0105x over previous
//
#include <hip/hip_runtime.h>
#include <hip/hip_bf16.h>

#define J_DIM 25
#define T_DIM 120
#define O_DIM 64
#define KPAD  328        // bf16 per ys/Wf row; 656 B = 41*16 (b128-aligned)
#define TB    64         // t-rows per block; chunks t0 = 0, 56 (8 dup rows, benign)
#define WROWS 68         // staged window rows (row + w <= 67)
#define XPAD  20         // xs row pad (floats); 4q offsets stay 16B-aligned

typedef __attribute__((ext_vector_type(8))) short bf16x8;
typedef __attribute__((ext_vector_type(4))) float f32x4;

__device__ __forceinline__ unsigned f2bf(float f) {
    union { float f; unsigned u; } v; v.f = f;
    return (v.u + 0x7FFFu + ((v.u >> 16) & 1u)) >> 16;
}
__device__ __forceinline__ unsigned pk2(float lo, float hi) {
    __hip_bfloat162 h = __float22bfloat162_rn(float2{lo, hi});
    unsigned u;
    __builtin_memcpy(&u, &h, 4);
    return u;
}

// ---- W (306x64 f32) -> Wf[o][k], k = 18a + b; b<17: 0.5*W2[a,b]; b==17: W1[a] ----
__global__ void wprep(const float* __restrict__ W, unsigned short* __restrict__ Wf) {
    int i = blockIdx.x * 256 + threadIdx.x;
    if (i >= O_DIM * KPAD) return;
    int o = i / KPAD, k = i % KPAD;
    int a = k / 18, b = k % 18;
    float v = 0.0f;
    if (k < 306) v = (b == 17) ? W[a * O_DIM + o] : 0.5f * W[(17 + 17 * a + b) * O_DIM + o];
    Wf[o * KPAD + k] = (unsigned short)f2bf(v);
}

// ---- main: block = (n, j, 64-row half); 256 threads; flat 2-barrier structure ----
// Baked-in lessons: launch_bounds must never clamp VGPR below need (R6/R10 spill
// catastrophe); phase-1 is STRAIGHT-LINE, one slot per thread — no loops carrying
// live state (R8/R9/R13 spills); B-frag register reuse only in the short phase-2
// scope (R14 proven).
__global__ __launch_bounds__(256, 2) void sig_mfma(
    const float* __restrict__ x, const unsigned short* __restrict__ Wf,
    const float* __restrict__ bias, float* __restrict__ out)
{
    __shared__ float xs[WROWS][XPAD];            // 5,440 B
    __shared__ unsigned short ys[TB * KPAD];     // 41,984 B   (total 47.4 KB)

    const int tid = threadIdx.x;
    const int bid = blockIdx.x;
    const int half = bid & 1;
    const int j = (bid >> 1) % J_DIM;
    const int n = bid / (2 * J_DIM);
    const int t0 = half * 56;                    // halves overlap rows 56..63 (dup stores)
    const int wave = tid >> 6, lane = tid & 63;
    const int l15 = lane & 15, l4 = lane >> 4;

    // ---- stage xs[i][c] = x[n,c,j,clamp(t0-2+i)] ----
    const float* xbase = x + ((size_t)(n * 16) * J_DIM + j) * T_DIM;
    for (int idx = tid; idx < 16 * WROWS; idx += 256) {
        int c = idx / WROWS, i = idx % WROWS;
        int st = min(max(t0 - 2 + i, 0), T_DIM - 1);
        xs[i][c] = xbase[(size_t)c * J_DIM * T_DIM + st];
    }
    // zero pad bytes [608,656) of every row (608-611 re-written by time-row store)
    if (tid < TB * 3) {
        int r = tid / 3, p = tid % 3;
        *(uint4*)((char*)ys + r * 656 + 608 + p * 16) = uint4{0, 0, 0, 0};
    }
    __syncthreads();

    // ---- phase 1: ONE slot per thread: (row = tid>>2, q = tid&3) -> a = 4q..4q+3 ----
    // S2[a,b] = sum_w h_w[a] * p_w[b],  h = (-p1, p0-p2, p1-p3, p2-p4, p3+p4)
    // q==3 additionally computes the time row a=16 (exec-masked, once per t).
    {
        const int row = tid >> 2, q = tid & 3;
        const int t = t0 + row;
        const int start = max(t - 2, 0), end = min(t + 3, T_DIM);
        const float inv = 1.0f / (float)(end - start - 1);
        const bool doT = (q == 3);
        float ptv[5];
        #pragma unroll
        for (int w = 0; w < 5; ++w) {
            int pcw = min(max(t - 2 + w, 0), T_DIM - 1);
            ptv[w] = (float)(pcw - start) * inv;
        }
        float4 paw[5];                           // window row w: rows 4q..4q+3
        #pragma unroll
        for (int w = 0; w < 5; ++w)
            paw[w] = *(const float4*)&xs[row + w][4 * q];

        float h0[5], h1[5], h2[5], h3[5], ht[5];
        h0[0] = -paw[1].x;          h1[0] = -paw[1].y;          h2[0] = -paw[1].z;          h3[0] = -paw[1].w;
        h0[1] = paw[0].x - paw[2].x; h1[1] = paw[0].y - paw[2].y; h2[1] = paw[0].z - paw[2].z; h3[1] = paw[0].w - paw[2].w;
        h0[2] = paw[1].x - paw[3].x; h1[2] = paw[1].y - paw[3].y; h2[2] = paw[1].z - paw[3].z; h3[2] = paw[1].w - paw[3].w;
        h0[3] = paw[2].x - paw[4].x; h1[3] = paw[2].y - paw[4].y; h2[3] = paw[2].z - paw[4].z; h3[3] = paw[2].w - paw[4].w;
        h0[4] = paw[3].x + paw[4].x; h1[4] = paw[3].y + paw[4].y; h2[4] = paw[3].z + paw[4].z; h3[4] = paw[3].w + paw[4].w;
        if (doT) {
            ht[0] = -ptv[1];
            ht[1] = ptv[0] - ptv[2];
            ht[2] = ptv[1] - ptv[3];
            ht[3] = ptv[2] - ptv[4];
            ht[4] = ptv[3] + ptv[4];
        }

        unsigned u0[9], u1[9], u2[9], u3[9], ut[9];
        float ac0 = 0, ac1 = 0, ac2 = 0, ac3 = 0, act = 0;
        #pragma unroll
        for (int hb = 0; hb < 2; ++hb) {
            float4 xw[5][2];
            #pragma unroll
            for (int w = 0; w < 5; ++w) {
                const float* rw = &xs[row + w][0];
                xw[w][0] = *(const float4*)(rw + 8 * hb);
                xw[w][1] = *(const float4*)(rw + 8 * hb + 4);
            }
            #pragma unroll
            for (int b8 = 0; b8 < 8; ++b8) {
                float pb[5];
                #pragma unroll
                for (int w = 0; w < 5; ++w) {
                    float4 v = xw[w][b8 >> 2];
                    pb[w] = ((b8 & 3) == 0) ? v.x : ((b8 & 3) == 1) ? v.y
                          : ((b8 & 3) == 2) ? v.z : v.w;
                }
                float a0 = h0[0] * pb[0], a1 = h1[0] * pb[0];
                float a2 = h2[0] * pb[0], a3 = h3[0] * pb[0];
                #pragma unroll
                for (int w = 1; w < 5; ++w) {
                    a0 = fmaf(h0[w], pb[w], a0);
                    a1 = fmaf(h1[w], pb[w], a1);
                    a2 = fmaf(h2[w], pb[w], a2);
                    a3 = fmaf(h3[w], pb[w], a3);
                }
                float at = 0;
                if (doT) {
                    at = ht[0] * pb[0];
                    #pragma unroll
                    for (int w = 1; w < 5; ++w) at = fmaf(ht[w], pb[w], at);
                }
                const int b = hb * 8 + b8;
                if (b & 1) {
                    const int m = b >> 1;
                    u0[m] = pk2(ac0, a0);
                    u1[m] = pk2(ac1, a1);
                    u2[m] = pk2(ac2, a2);
                    u3[m] = pk2(ac3, a3);
                    if (doT) ut[m] = pk2(act, at);
                } else { ac0 = a0; ac1 = a1; ac2 = a2; ac3 = a3; act = at; }
            }
        }
        {   // b = 16 (time column) + S1 slot
            float a0 = h0[0] * ptv[0], a1 = h1[0] * ptv[0];
            float a2 = h2[0] * ptv[0], a3 = h3[0] * ptv[0];
            #pragma unroll
            for (int w = 1; w < 5; ++w) {
                a0 = fmaf(h0[w], ptv[w], a0);
                a1 = fmaf(h1[w], ptv[w], a1);
                a2 = fmaf(h2[w], ptv[w], a2);
                a3 = fmaf(h3[w], ptv[w], a3);
            }
            u0[8] = pk2(a0, paw[4].x);
            u1[8] = pk2(a1, paw[4].y);
            u2[8] = pk2(a2, paw[4].z);
            u3[8] = pk2(a3, paw[4].w);
            if (doT) {
                float at = ht[0] * ptv[0];
                #pragma unroll
                for (int w = 1; w < 5; ++w) at = fmaf(ht[w], ptv[w], at);
                ut[8] = pk2(at, ptv[4]);
            }
        }
        // rows 4q..4q+3 = k [72q, 72q+72): contiguous 144 B -> 9 x b128
        char* yr = (char*)ys + row * 656 + q * 144;
        *(uint4*)(yr +   0) = uint4{u0[0], u0[1], u0[2], u0[3]};
        *(uint4*)(yr +  16) = uint4{u0[4], u0[5], u0[6], u0[7]};
        *(uint4*)(yr +  32) = uint4{u0[8], u1[0], u1[1], u1[2]};
        *(uint4*)(yr +  48) = uint4{u1[3], u1[4], u1[5], u1[6]};
        *(uint4*)(yr +  64) = uint4{u1[7], u1[8], u2[0], u2[1]};
        *(uint4*)(yr +  80) = uint4{u2[2], u2[3], u2[4], u2[5]};
        *(uint4*)(yr +  96) = uint4{u2[6], u2[7], u2[8], u3[0]};
        *(uint4*)(yr + 112) = uint4{u3[1], u3[2], u3[3], u3[4]};
        *(uint4*)(yr + 128) = uint4{u3[5], u3[6], u3[7], u3[8]};
        if (doT) {                               // time row a=16 at bytes [576,612)
            char* yt = (char*)ys + row * 656 + 576;
            *(uint4*)(yt +  0) = uint4{ut[0], ut[1], ut[2], ut[3]};
            *(uint4*)(yt + 16) = uint4{ut[4], ut[5], ut[6], ut[7]};
            *(unsigned*)(yt + 32) = ut[8];
        }
    }
    __syncthreads();

    // ---- phase 2: wave = o-quarter; B-frags loaded once, reused over 4 M-tiles ----
    {
        const float bv = bias[wave * 16 + l15];
        const unsigned short* Bb = Wf + (size_t)(wave * 16 + l15) * KPAD + l4 * 8;
        bf16x8 bfrag[10];
        #pragma unroll
        for (int kk = 0; kk < 10; ++kk)
            bfrag[kk] = *(const bf16x8*)(Bb + kk * 32);
        #pragma unroll
        for (int mi = 0; mi < 4; ++mi) {
            const char* Ab = (const char*)ys + (mi * 16 + l15) * 656 + l4 * 16;
            f32x4 acc = f32x4{bv, bv, bv, bv};
            #pragma unroll
            for (int kk = 0; kk < 10; ++kk) {
                bf16x8 af = *(const bf16x8*)(Ab + kk * 64);
                acc = __builtin_amdgcn_mfma_f32_16x16x32_bf16(af, bfrag[kk], acc, 0, 0, 0);
            }
            const int tg = t0 + mi * 16 + l4 * 4;    // row = l4*4 + reg -> t
            float* op = out + ((size_t)(n * O_DIM + wave * 16 + l15) * J_DIM + j) * T_DIM + tg;
            *(f32x4*)op = acc;
        }
    }
}

extern "C" void kernel_launch(void* const* d_in, const int* in_sizes, int n_in,
                              void* d_out, int out_size, void* d_ws, size_t ws_size,
                              hipStream_t stream) {
    const float* x = (const float*)d_in[0];
    const float* W = (const float*)d_in[1];
    const float* b = (const float*)d_in[2];
    float* out = (float*)d_out;
    unsigned short* Wf = (unsigned short*)d_ws;   // 64*328*2 = 41,984 B

    wprep<<<(O_DIM * KPAD + 255) / 256, 256, 0, stream>>>(W, Wf);
    sig_mfma<<<64 * J_DIM * 2, 256, 0, stream>>>(x, Wf, b, out);
}